// Round 3
// baseline (857.528 us; speedup 1.0000x reference)
//
#include <hip/hip_runtime.h>
#include <hip/hip_bf16.h>

#define N_NODES 100000
#define IN_DIM 128
#define OUT_DIM 32
#define NEG_SLOPE 0.01f

__device__ __forceinline__ float bfu2f(unsigned int u16) {
    union { unsigned int i; float f; } v;
    v.i = u16 << 16;
    return v.f;
}
__device__ __forceinline__ unsigned short f2bfu(float f) {
    union { unsigned int i; float f; } v;
    v.f = f;
    unsigned int r = v.i + 0x7fffu + ((v.i >> 16) & 1u);  // RNE
    return (unsigned short)(r >> 16);
}

// K1: z = h @ fc_w^T (per-thread node; fc_w staged fp32 in LDS, broadcast reads).
// Stores z packed bf16 (ws), s_l/s_r fp32, zeroes denom and the out row.
__global__ __launch_bounds__(256) void k1_z_scores(
    const float* __restrict__ h,
    const float* __restrict__ fc_w,
    const float* __restrict__ attn_w,
    unsigned short* __restrict__ zbf,
    float* __restrict__ s_l,
    float* __restrict__ s_r,
    float* __restrict__ denom,
    float* __restrict__ out) {
    __shared__ float wlds[OUT_DIM * IN_DIM];   // 16 KB
    __shared__ float al[OUT_DIM], ar[OUT_DIM];

    const int tid = threadIdx.x;
    for (int i = tid; i < OUT_DIM * IN_DIM; i += 256) wlds[i] = fc_w[i];
    if (tid < OUT_DIM) {
        al[tid] = attn_w[tid];
        ar[tid] = attn_w[OUT_DIM + tid];
    }
    __syncthreads();

    const int node = blockIdx.x * 256 + tid;
    if (node >= N_NODES) return;

    float acc[OUT_DIM];
#pragma unroll
    for (int j = 0; j < OUT_DIM; ++j) acc[j] = 0.f;

    const float4* hp = (const float4*)(h + (size_t)node * IN_DIM);
#pragma unroll 4
    for (int kg = 0; kg < IN_DIM / 4; ++kg) {
        const float4 hv = hp[kg];
#pragma unroll
        for (int j = 0; j < OUT_DIM; ++j) {
            const float4 w = *(const float4*)&wlds[j * IN_DIM + kg * 4];
            acc[j] += hv.x * w.x + hv.y * w.y + hv.z * w.z + hv.w * w.w;
        }
    }

    float sl = 0.f, sr = 0.f;
#pragma unroll
    for (int j = 0; j < OUT_DIM; ++j) {
        sl += acc[j] * al[j];
        sr += acc[j] * ar[j];
    }
    s_l[node] = sl;
    s_r[node] = sr;
    denom[node] = 0.f;

    // pack 32 bf16 = 4 x uint4
    uint4* zp = (uint4*)(zbf + (size_t)node * OUT_DIM);
#pragma unroll
    for (int q = 0; q < 4; ++q) {
        uint4 pk;
        pk.x = (unsigned int)f2bfu(acc[8 * q + 0]) | ((unsigned int)f2bfu(acc[8 * q + 1]) << 16);
        pk.y = (unsigned int)f2bfu(acc[8 * q + 2]) | ((unsigned int)f2bfu(acc[8 * q + 3]) << 16);
        pk.z = (unsigned int)f2bfu(acc[8 * q + 4]) | ((unsigned int)f2bfu(acc[8 * q + 5]) << 16);
        pk.w = (unsigned int)f2bfu(acc[8 * q + 6]) | ((unsigned int)f2bfu(acc[8 * q + 7]) << 16);
        zp[q] = pk;
    }

    float4* op = (float4*)(out + (size_t)node * OUT_DIM);
    const float4 zero4 = make_float4(0.f, 0.f, 0.f, 0.f);
#pragma unroll
    for (int q = 0; q < 8; ++q) op[q] = zero4;
}

// K3: one edge per 8 lanes; lane q covers dims 4q..4q+3 (uint2 = 4 bf16).
// w = exp(leaky_relu(s_l[src]+s_r[dst])); no max-subtraction (|score| <~20).
// out[dst][j] += w * z[src][j]; denom[dst] += w.
__global__ __launch_bounds__(256) void k3_edges(
    const int* __restrict__ src,
    const int* __restrict__ dst,
    const float* __restrict__ s_l,
    const float* __restrict__ s_r,
    const unsigned short* __restrict__ zbf,
    float* __restrict__ denom,
    float* __restrict__ out,
    int E) {
    const long long gid = (long long)blockIdx.x * 256 + threadIdx.x;
    const int e = (int)(gid >> 3);
    const int q = (int)(gid & 7);      // which group of 4 dims
    if (e >= E) return;

    const int s = src[e];
    const int d = dst[e];
    float x = s_l[s] + s_r[d];
    x = (x > 0.f) ? x : NEG_SLOPE * x;
    const float w = __expf(x);

    const uint2 zv = *(const uint2*)&zbf[(size_t)s * OUT_DIM + q * 4];
    const float z0 = bfu2f(zv.x & 0xffffu), z1 = bfu2f(zv.x >> 16);
    const float z2 = bfu2f(zv.y & 0xffffu), z3 = bfu2f(zv.y >> 16);

    float* op = &out[(size_t)d * OUT_DIM + q * 4];
    unsafeAtomicAdd(op + 0, w * z0);
    unsafeAtomicAdd(op + 1, w * z1);
    unsafeAtomicAdd(op + 2, w * z2);
    unsafeAtomicAdd(op + 3, w * z3);
    if (q == 0) unsafeAtomicAdd(&denom[d], w);
}

// K4: out[n][j] /= denom[n] in place; empty segments -> 0.
__global__ __launch_bounds__(256) void k4_finalize(
    const float* __restrict__ denom,
    float* __restrict__ out) {
    const int i = blockIdx.x * 256 + threadIdx.x;
    if (i >= N_NODES * OUT_DIM) return;
    const int n = i >> 5;
    const float dnm = denom[n];
    out[i] = (dnm > 0.f) ? out[i] / dnm : 0.f;
}

extern "C" void kernel_launch(void* const* d_in, const int* in_sizes, int n_in,
                              void* d_out, int out_size, void* d_ws, size_t ws_size,
                              hipStream_t stream) {
    const float* h      = (const float*)d_in[0];
    const int*   src    = (const int*)d_in[1];
    const int*   dst    = (const int*)d_in[2];
    const float* fc_w   = (const float*)d_in[3];
    const float* attn_w = (const float*)d_in[4];
    float* out = (float*)d_out;
    const int E = (in_sizes[1] > 0) ? in_sizes[1] : 1600000;

    // ws footprint: 6.4 MB (zbf) + 3*0.4 MB = 7.6 MB total.
    char* ws = (char*)d_ws;
    size_t off = 0;
    unsigned short* zbf = (unsigned short*)(ws + off); off += (size_t)N_NODES * OUT_DIM * sizeof(unsigned short);
    float* s_l = (float*)(ws + off);   off += (size_t)N_NODES * sizeof(float);
    float* s_r = (float*)(ws + off);   off += (size_t)N_NODES * sizeof(float);
    float* denom = (float*)(ws + off); off += (size_t)N_NODES * sizeof(float);

    const int blocks_k1 = (N_NODES + 255) / 256;
    k1_z_scores<<<blocks_k1, 256, 0, stream>>>(h, fc_w, attn_w, zbf, s_l, s_r, denom, out);

    const long long tot = (long long)E * 8;
    const int blocks_k3 = (int)((tot + 255) / 256);
    k3_edges<<<blocks_k3, 256, 0, stream>>>(src, dst, s_l, s_r, zbf, denom, out, E);

    const int blocks_k4 = (N_NODES * OUT_DIM + 255) / 256;
    k4_finalize<<<blocks_k4, 256, 0, stream>>>(denom, out);
}

// Round 4
// 620.749 us; speedup vs baseline: 1.3814x; 1.3814x over previous
//
#include <hip/hip_runtime.h>
#include <hip/hip_bf16.h>

#define N_NODES 100000
#define IN_DIM 128
#define OUT_DIM 32
#define NEG_SLOPE 0.01f
#define E_DEFAULT 1600000

__device__ __forceinline__ float bfu2f(unsigned int u16) {
    union { unsigned int i; float f; } v;
    v.i = u16 << 16;
    return v.f;
}
__device__ __forceinline__ unsigned short f2bfu(float f) {
    union { unsigned int i; float f; } v;
    v.f = f;
    unsigned int r = v.i + 0x7fffu + ((v.i >> 16) & 1u);  // RNE
    return (unsigned short)(r >> 16);
}

// K1: z = h @ fc_w^T (per-thread node; fc_w staged fp32 in LDS, broadcast reads).
// Stores z packed bf16, s_l/s_r fp32. mode 0 (CSR): zero counts[node].
// mode 1 (atomic fallback): zero denom[node] and out row.
__global__ __launch_bounds__(256) void k1_z_scores(
    const float* __restrict__ h,
    const float* __restrict__ fc_w,
    const float* __restrict__ attn_w,
    unsigned short* __restrict__ zbf,
    float* __restrict__ s_l,
    float* __restrict__ s_r,
    int* __restrict__ counts,
    float* __restrict__ denom,
    float* __restrict__ out,
    int mode) {
    __shared__ float wlds[OUT_DIM * IN_DIM];   // 16 KB
    __shared__ float al[OUT_DIM], ar[OUT_DIM];

    const int tid = threadIdx.x;
    for (int i = tid; i < OUT_DIM * IN_DIM; i += 256) wlds[i] = fc_w[i];
    if (tid < OUT_DIM) {
        al[tid] = attn_w[tid];
        ar[tid] = attn_w[OUT_DIM + tid];
    }
    __syncthreads();

    const int node = blockIdx.x * 256 + tid;
    if (node >= N_NODES) return;

    float acc[OUT_DIM];
#pragma unroll
    for (int j = 0; j < OUT_DIM; ++j) acc[j] = 0.f;

    const float4* hp = (const float4*)(h + (size_t)node * IN_DIM);
#pragma unroll 4
    for (int kg = 0; kg < IN_DIM / 4; ++kg) {
        const float4 hv = hp[kg];
#pragma unroll
        for (int j = 0; j < OUT_DIM; ++j) {
            const float4 w = *(const float4*)&wlds[j * IN_DIM + kg * 4];
            acc[j] += hv.x * w.x + hv.y * w.y + hv.z * w.z + hv.w * w.w;
        }
    }

    float sl = 0.f, sr = 0.f;
#pragma unroll
    for (int j = 0; j < OUT_DIM; ++j) {
        sl += acc[j] * al[j];
        sr += acc[j] * ar[j];
    }
    s_l[node] = sl;
    s_r[node] = sr;

    uint4* zp = (uint4*)(zbf + (size_t)node * OUT_DIM);
#pragma unroll
    for (int q = 0; q < 4; ++q) {
        uint4 pk;
        pk.x = (unsigned int)f2bfu(acc[8 * q + 0]) | ((unsigned int)f2bfu(acc[8 * q + 1]) << 16);
        pk.y = (unsigned int)f2bfu(acc[8 * q + 2]) | ((unsigned int)f2bfu(acc[8 * q + 3]) << 16);
        pk.z = (unsigned int)f2bfu(acc[8 * q + 4]) | ((unsigned int)f2bfu(acc[8 * q + 5]) << 16);
        pk.w = (unsigned int)f2bfu(acc[8 * q + 6]) | ((unsigned int)f2bfu(acc[8 * q + 7]) << 16);
        zp[q] = pk;
    }

    if (mode == 0) {
        counts[node] = 0;
    } else {
        denom[node] = 0.f;
        float4* op = (float4*)(out + (size_t)node * OUT_DIM);
        const float4 zero4 = make_float4(0.f, 0.f, 0.f, 0.f);
#pragma unroll
        for (int q = 0; q < 8; ++q) op[q] = zero4;
    }
}

// ---------------- CSR path ----------------

__global__ __launch_bounds__(256) void k_hist(
    const int* __restrict__ dst, int* __restrict__ counts, int E) {
    const int e = blockIdx.x * 256 + threadIdx.x;
    if (e < E) atomicAdd(&counts[dst[e]], 1);
}

// Single-block exclusive scan over counts -> start[0..N]; counts becomes cursor.
__global__ __launch_bounds__(1024) void k_scan(
    int* __restrict__ cnt_cur, int* __restrict__ start) {
    __shared__ int part[1024];
    const int T = 1024;
    const int t = threadIdx.x;
    const int chunk = (N_NODES + T - 1) / T;
    const int lo = t * chunk;
    const int hi = (lo + chunk < N_NODES) ? lo + chunk : N_NODES;
    int s = 0;
    for (int i = lo; i < hi; ++i) s += cnt_cur[i];
    part[t] = s;
    __syncthreads();
    for (int offs = 1; offs < T; offs <<= 1) {
        int v = (t >= offs) ? part[t - offs] : 0;
        __syncthreads();
        part[t] += v;
        __syncthreads();
    }
    int run = (t == 0) ? 0 : part[t - 1];
    for (int i = lo; i < hi; ++i) {
        int c = cnt_cur[i];
        start[i] = run;
        cnt_cur[i] = run;   // cursor init
        run += c;
    }
    if (t == T - 1) start[N_NODES] = run;
}

__global__ __launch_bounds__(256) void k_scatter(
    const int* __restrict__ src, const int* __restrict__ dst,
    int* __restrict__ cursor, int* __restrict__ esrc, int E) {
    const int e = blockIdx.x * 256 + threadIdx.x;
    if (e >= E) return;
    const int pos = atomicAdd(&cursor[dst[e]], 1);
    esrc[pos] = src[e];
}

// One wave per node: 64 lanes = 2 edges x 32 dims. Atomic-free accumulate,
// fused divide + store. w recomputed from L2-resident s_l (400 KB).
__global__ __launch_bounds__(256) void k_gather(
    const int* __restrict__ start,
    const int* __restrict__ esrc,
    const float* __restrict__ s_l,
    const float* __restrict__ s_r,
    const unsigned short* __restrict__ zbf,
    float* __restrict__ out) {
    const int gtid = blockIdx.x * 256 + threadIdx.x;
    const int n = gtid >> 6;
    if (n >= N_NODES) return;
    const int lane = gtid & 63;
    const int half = lane >> 5;
    const int dim = lane & 31;

    const int st = start[n];
    const int cnt = start[n + 1] - st;
    const float sr_n = s_r[n];

    float acc = 0.f, dn = 0.f;
    for (int i = half; i < cnt; i += 2) {
        const int es = esrc[st + i];
        float x = s_l[es] + sr_n;
        x = (x > 0.f) ? x : NEG_SLOPE * x;
        const float w = __expf(x);
        acc += w * bfu2f(zbf[(size_t)es * OUT_DIM + dim]);
        dn += w;
    }
    acc += __shfl_xor(acc, 32, 64);
    dn += __shfl_xor(dn, 32, 64);
    if (lane < 32) {
        out[(size_t)n * OUT_DIM + dim] = (dn > 0.f) ? acc / dn : 0.f;
    }
}

// ---------------- atomic fallback path (known-passing round-3 code) ----------

__global__ __launch_bounds__(256) void k3_edges(
    const int* __restrict__ src,
    const int* __restrict__ dst,
    const float* __restrict__ s_l,
    const float* __restrict__ s_r,
    const unsigned short* __restrict__ zbf,
    float* __restrict__ denom,
    float* __restrict__ out,
    int E) {
    const long long gid = (long long)blockIdx.x * 256 + threadIdx.x;
    const int e = (int)(gid >> 3);
    const int q = (int)(gid & 7);
    if (e >= E) return;

    const int s = src[e];
    const int d = dst[e];
    float x = s_l[s] + s_r[d];
    x = (x > 0.f) ? x : NEG_SLOPE * x;
    const float w = __expf(x);

    const uint2 zv = *(const uint2*)&zbf[(size_t)s * OUT_DIM + q * 4];
    float* op = &out[(size_t)d * OUT_DIM + q * 4];
    unsafeAtomicAdd(op + 0, w * bfu2f(zv.x & 0xffffu));
    unsafeAtomicAdd(op + 1, w * bfu2f(zv.x >> 16));
    unsafeAtomicAdd(op + 2, w * bfu2f(zv.y & 0xffffu));
    unsafeAtomicAdd(op + 3, w * bfu2f(zv.y >> 16));
    if (q == 0) unsafeAtomicAdd(&denom[d], w);
}

__global__ __launch_bounds__(256) void k4_finalize(
    const float* __restrict__ denom, float* __restrict__ out) {
    const int i = blockIdx.x * 256 + threadIdx.x;
    if (i >= N_NODES * OUT_DIM) return;
    const float dnm = denom[i >> 5];
    out[i] = (dnm > 0.f) ? out[i] / dnm : 0.f;
}

extern "C" void kernel_launch(void* const* d_in, const int* in_sizes, int n_in,
                              void* d_out, int out_size, void* d_ws, size_t ws_size,
                              hipStream_t stream) {
    const float* h      = (const float*)d_in[0];
    const int*   src    = (const int*)d_in[1];
    const int*   dst    = (const int*)d_in[2];
    const float* fc_w   = (const float*)d_in[3];
    const float* attn_w = (const float*)d_in[4];
    float* out = (float*)d_out;
    const int E = (in_sizes[1] > 0) ? in_sizes[1] : E_DEFAULT;

    char* ws = (char*)d_ws;
    size_t off = 0;
    unsigned short* zbf = (unsigned short*)(ws + off);
    off += (size_t)N_NODES * OUT_DIM * sizeof(unsigned short);      // 6.4 MB
    float* s_l = (float*)(ws + off); off += (size_t)N_NODES * 4;    // 0.4 MB
    float* s_r = (float*)(ws + off); off += (size_t)N_NODES * 4;    // 0.4 MB

    // CSR extras
    const size_t base = off;
    int* counts = (int*)(ws + off);  off += (size_t)N_NODES * 4;    // 0.4 MB (also cursor)
    int* start  = (int*)(ws + off);  off += ((size_t)N_NODES + 4) * 4;
    int* esrc   = (int*)(ws + off);  off += (size_t)E * 4;          // 6.4 MB
    const size_t csr_total = off;
    // fallback aliases denom over the CSR region
    float* denom = (float*)(ws + base);

    const bool use_csr = (ws_size >= csr_total);
    const int blocks_k1 = (N_NODES + 255) / 256;
    const int blocks_e = (E + 255) / 256;

    if (use_csr) {
        k1_z_scores<<<blocks_k1, 256, 0, stream>>>(h, fc_w, attn_w, zbf, s_l, s_r,
                                                   counts, nullptr, nullptr, 0);
        k_hist<<<blocks_e, 256, 0, stream>>>(dst, counts, E);
        k_scan<<<1, 1024, 0, stream>>>(counts, start);
        k_scatter<<<blocks_e, 256, 0, stream>>>(src, dst, counts, esrc, E);
        const int blocks_g = (N_NODES * 64 + 255) / 256;
        k_gather<<<blocks_g, 256, 0, stream>>>(start, esrc, s_l, s_r, zbf, out);
    } else {
        k1_z_scores<<<blocks_k1, 256, 0, stream>>>(h, fc_w, attn_w, zbf, s_l, s_r,
                                                   nullptr, denom, out, 1);
        const long long tot = (long long)E * 8;
        const int blocks_k3 = (int)((tot + 255) / 256);
        k3_edges<<<blocks_k3, 256, 0, stream>>>(src, dst, s_l, s_r, zbf, denom, out, E);
        const int blocks_k4 = (N_NODES * OUT_DIM + 255) / 256;
        k4_finalize<<<blocks_k4, 256, 0, stream>>>(denom, out);
    }
}

// Round 5
// 406.227 us; speedup vs baseline: 2.1110x; 1.5281x over previous
//
#include <hip/hip_runtime.h>
#include <hip/hip_bf16.h>

#define N_NODES 100000
#define IN_DIM 128
#define OUT_DIM 32
#define NEG_SLOPE 0.01f
#define E_DEFAULT 1600000
#define SCAN_CHUNK 256
#define SCAN_NBLK ((N_NODES + SCAN_CHUNK - 1) / SCAN_CHUNK)   // 391

__device__ __forceinline__ float bfu2f(unsigned int u16) {
    union { unsigned int i; float f; } v;
    v.i = u16 << 16;
    return v.f;
}
__device__ __forceinline__ unsigned short f2bfu(float f) {
    union { unsigned int i; float f; } v;
    v.f = f;
    unsigned int r = v.i + 0x7fffu + ((v.i >> 16) & 1u);  // RNE
    return (unsigned short)(r >> 16);
}

// K1: z = h @ fc_w^T. 2 nodes per thread (each LDS weight read amortized over
// both). Stores z packed bf16, s_l/s_r fp32; zeroes counts (CSR) or denom/out.
__global__ __launch_bounds__(256) void k1_z_scores(
    const float* __restrict__ h,
    const float* __restrict__ fc_w,
    const float* __restrict__ attn_w,
    unsigned short* __restrict__ zbf,
    float* __restrict__ s_l,
    float* __restrict__ s_r,
    int* __restrict__ counts,
    float* __restrict__ denom,
    float* __restrict__ out,
    int mode) {
    __shared__ float wlds[OUT_DIM * IN_DIM];   // 16 KB
    __shared__ float al[OUT_DIM], ar[OUT_DIM];

    const int tid = threadIdx.x;
    for (int i = tid; i < OUT_DIM * IN_DIM; i += 256) wlds[i] = fc_w[i];
    if (tid < OUT_DIM) {
        al[tid] = attn_w[tid];
        ar[tid] = attn_w[OUT_DIM + tid];
    }
    __syncthreads();

    const int n0 = blockIdx.x * 512 + tid;
    const int n1 = n0 + 256;
    const bool v0 = (n0 < N_NODES);
    const bool v1 = (n1 < N_NODES);
    if (!v0) return;

    float acc0[OUT_DIM], acc1[OUT_DIM];
#pragma unroll
    for (int j = 0; j < OUT_DIM; ++j) { acc0[j] = 0.f; acc1[j] = 0.f; }

    const float4* hp0 = (const float4*)(h + (size_t)n0 * IN_DIM);
    const float4* hp1 = (const float4*)(h + (size_t)(v1 ? n1 : n0) * IN_DIM);

#pragma unroll 2
    for (int kg = 0; kg < IN_DIM / 4; ++kg) {
        const float4 ha = hp0[kg];
        const float4 hb = hp1[kg];
#pragma unroll
        for (int j = 0; j < OUT_DIM; ++j) {
            const float4 w = *(const float4*)&wlds[j * IN_DIM + kg * 4];
            acc0[j] += ha.x * w.x + ha.y * w.y + ha.z * w.z + ha.w * w.w;
            acc1[j] += hb.x * w.x + hb.y * w.y + hb.z * w.z + hb.w * w.w;
        }
    }

    // epilogue for a node
    for (int pass = 0; pass < 2; ++pass) {
        const int node = pass ? n1 : n0;
        if (pass && !v1) break;
        const float* acc = pass ? acc1 : acc0;
        float sl = 0.f, sr = 0.f;
#pragma unroll
        for (int j = 0; j < OUT_DIM; ++j) {
            sl += acc[j] * al[j];
            sr += acc[j] * ar[j];
        }
        s_l[node] = sl;
        s_r[node] = sr;

        uint4* zp = (uint4*)(zbf + (size_t)node * OUT_DIM);
#pragma unroll
        for (int q = 0; q < 4; ++q) {
            uint4 pk;
            pk.x = (unsigned int)f2bfu(acc[8 * q + 0]) | ((unsigned int)f2bfu(acc[8 * q + 1]) << 16);
            pk.y = (unsigned int)f2bfu(acc[8 * q + 2]) | ((unsigned int)f2bfu(acc[8 * q + 3]) << 16);
            pk.z = (unsigned int)f2bfu(acc[8 * q + 4]) | ((unsigned int)f2bfu(acc[8 * q + 5]) << 16);
            pk.w = (unsigned int)f2bfu(acc[8 * q + 6]) | ((unsigned int)f2bfu(acc[8 * q + 7]) << 16);
            zp[q] = pk;
        }

        if (mode == 0) {
            counts[node] = 0;
        } else {
            denom[node] = 0.f;
            float4* op = (float4*)(out + (size_t)node * OUT_DIM);
            const float4 zero4 = make_float4(0.f, 0.f, 0.f, 0.f);
#pragma unroll
            for (int q = 0; q < 8; ++q) op[q] = zero4;
        }
    }
}

// ---------------- CSR path ----------------

__global__ __launch_bounds__(256) void k_hist(
    const int* __restrict__ dst, int* __restrict__ counts, int E) {
    const int e = blockIdx.x * 256 + threadIdx.x;
    if (e < E) atomicAdd(&counts[dst[e]], 1);
}

// Hierarchical scan, phase 1: per-block (256-elem chunk) sums, coalesced.
__global__ __launch_bounds__(256) void k_reduce(
    const int* __restrict__ counts, int* __restrict__ bsum) {
    __shared__ int red[4];
    const int i = blockIdx.x * 256 + threadIdx.x;
    int v = (i < N_NODES) ? counts[i] : 0;
#pragma unroll
    for (int o = 32; o > 0; o >>= 1) v += __shfl_down(v, o, 64);
    const int lane = threadIdx.x & 63;
    const int w = threadIdx.x >> 6;
    if (lane == 0) red[w] = v;
    __syncthreads();
    if (threadIdx.x == 0) bsum[blockIdx.x] = red[0] + red[1] + red[2] + red[3];
}

// Phase 2: one block scans the 391 block sums -> exclusive prefixes + total.
__global__ __launch_bounds__(512) void k_scan_top(
    const int* __restrict__ bsum, int* __restrict__ bpre, int* __restrict__ start) {
    __shared__ int sc[512];
    const int t = threadIdx.x;
    const int v = (t < SCAN_NBLK) ? bsum[t] : 0;
    sc[t] = v;
    __syncthreads();
    for (int off = 1; off < 512; off <<= 1) {
        const int u = (t >= off) ? sc[t - off] : 0;
        __syncthreads();
        sc[t] += u;
        __syncthreads();
    }
    if (t < SCAN_NBLK) bpre[t] = sc[t] - v;   // exclusive
    if (t == 511) start[N_NODES] = sc[511];   // total
}

// Phase 3: per-chunk exclusive scan + block offset -> start[] and cursor[].
__global__ __launch_bounds__(256) void k_scan_down(
    int* __restrict__ cnt_cur,            // counts in, cursor out
    const int* __restrict__ bpre,
    int* __restrict__ start) {
    __shared__ int sc[256];
    const int t = threadIdx.x;
    const int i = blockIdx.x * 256 + t;
    const int v = (i < N_NODES) ? cnt_cur[i] : 0;
    sc[t] = v;
    __syncthreads();
    for (int off = 1; off < 256; off <<= 1) {
        const int u = (t >= off) ? sc[t - off] : 0;
        __syncthreads();
        sc[t] += u;
        __syncthreads();
    }
    if (i < N_NODES) {
        const int st = bpre[blockIdx.x] + sc[t] - v;
        start[i] = st;
        cnt_cur[i] = st;   // cursor init
    }
}

__global__ __launch_bounds__(256) void k_scatter(
    const int* __restrict__ src, const int* __restrict__ dst,
    int* __restrict__ cursor, int* __restrict__ esrc, int E) {
    const int e = blockIdx.x * 256 + threadIdx.x;
    if (e >= E) return;
    const int pos = atomicAdd(&cursor[dst[e]], 1);
    esrc[pos] = src[e];
}

// One wave per node: 64 lanes = 2 edges x 32 dims. Atomic-free accumulate,
// fused divide + store.
__global__ __launch_bounds__(256) void k_gather(
    const int* __restrict__ start,
    const int* __restrict__ esrc,
    const float* __restrict__ s_l,
    const float* __restrict__ s_r,
    const unsigned short* __restrict__ zbf,
    float* __restrict__ out) {
    const int gtid = blockIdx.x * 256 + threadIdx.x;
    const int n = gtid >> 6;
    if (n >= N_NODES) return;
    const int lane = gtid & 63;
    const int half = lane >> 5;
    const int dim = lane & 31;

    const int st = start[n];
    const int cnt = start[n + 1] - st;
    const float sr_n = s_r[n];

    float acc = 0.f, dn = 0.f;
    for (int i = half; i < cnt; i += 2) {
        const int es = esrc[st + i];
        float x = s_l[es] + sr_n;
        x = (x > 0.f) ? x : NEG_SLOPE * x;
        const float w = __expf(x);
        acc += w * bfu2f(zbf[(size_t)es * OUT_DIM + dim]);
        dn += w;
    }
    acc += __shfl_xor(acc, 32, 64);
    dn += __shfl_xor(dn, 32, 64);
    if (lane < 32) {
        out[(size_t)n * OUT_DIM + dim] = (dn > 0.f) ? acc / dn : 0.f;
    }
}

// ---------------- atomic fallback path (known-passing) ----------

__global__ __launch_bounds__(256) void k3_edges(
    const int* __restrict__ src,
    const int* __restrict__ dst,
    const float* __restrict__ s_l,
    const float* __restrict__ s_r,
    const unsigned short* __restrict__ zbf,
    float* __restrict__ denom,
    float* __restrict__ out,
    int E) {
    const long long gid = (long long)blockIdx.x * 256 + threadIdx.x;
    const int e = (int)(gid >> 3);
    const int q = (int)(gid & 7);
    if (e >= E) return;

    const int s = src[e];
    const int d = dst[e];
    float x = s_l[s] + s_r[d];
    x = (x > 0.f) ? x : NEG_SLOPE * x;
    const float w = __expf(x);

    const uint2 zv = *(const uint2*)&zbf[(size_t)s * OUT_DIM + q * 4];
    float* op = &out[(size_t)d * OUT_DIM + q * 4];
    unsafeAtomicAdd(op + 0, w * bfu2f(zv.x & 0xffffu));
    unsafeAtomicAdd(op + 1, w * bfu2f(zv.x >> 16));
    unsafeAtomicAdd(op + 2, w * bfu2f(zv.y & 0xffffu));
    unsafeAtomicAdd(op + 3, w * bfu2f(zv.y >> 16));
    if (q == 0) unsafeAtomicAdd(&denom[d], w);
}

__global__ __launch_bounds__(256) void k4_finalize(
    const float* __restrict__ denom, float* __restrict__ out) {
    const int i = blockIdx.x * 256 + threadIdx.x;
    if (i >= N_NODES * OUT_DIM) return;
    const float dnm = denom[i >> 5];
    out[i] = (dnm > 0.f) ? out[i] / dnm : 0.f;
}

extern "C" void kernel_launch(void* const* d_in, const int* in_sizes, int n_in,
                              void* d_out, int out_size, void* d_ws, size_t ws_size,
                              hipStream_t stream) {
    const float* h      = (const float*)d_in[0];
    const int*   src    = (const int*)d_in[1];
    const int*   dst    = (const int*)d_in[2];
    const float* fc_w   = (const float*)d_in[3];
    const float* attn_w = (const float*)d_in[4];
    float* out = (float*)d_out;
    const int E = (in_sizes[1] > 0) ? in_sizes[1] : E_DEFAULT;

    char* ws = (char*)d_ws;
    size_t off = 0;
    unsigned short* zbf = (unsigned short*)(ws + off);
    off += (size_t)N_NODES * OUT_DIM * sizeof(unsigned short);      // 6.4 MB
    float* s_l = (float*)(ws + off); off += (size_t)N_NODES * 4;    // 0.4 MB
    float* s_r = (float*)(ws + off); off += (size_t)N_NODES * 4;    // 0.4 MB

    // CSR extras
    const size_t base = off;
    int* counts = (int*)(ws + off);  off += (size_t)N_NODES * 4;    // cursor too
    int* start  = (int*)(ws + off);  off += ((size_t)N_NODES + 4) * 4;
    int* esrc   = (int*)(ws + off);  off += (size_t)E * 4;          // 6.4 MB
    int* bsum   = (int*)(ws + off);  off += (size_t)SCAN_NBLK * 4;
    int* bpre   = (int*)(ws + off);  off += (size_t)SCAN_NBLK * 4;
    const size_t csr_total = off;
    float* denom = (float*)(ws + base);   // fallback aliases CSR region

    const bool use_csr = (ws_size >= csr_total);
    const int blocks_k1 = (N_NODES + 511) / 512;
    const int blocks_e = (E + 255) / 256;

    if (use_csr) {
        k1_z_scores<<<blocks_k1, 256, 0, stream>>>(h, fc_w, attn_w, zbf, s_l, s_r,
                                                   counts, nullptr, nullptr, 0);
        k_hist<<<blocks_e, 256, 0, stream>>>(dst, counts, E);
        k_reduce<<<SCAN_NBLK, 256, 0, stream>>>(counts, bsum);
        k_scan_top<<<1, 512, 0, stream>>>(bsum, bpre, start);
        k_scan_down<<<SCAN_NBLK, 256, 0, stream>>>(counts, bpre, start);
        k_scatter<<<blocks_e, 256, 0, stream>>>(src, dst, counts, esrc, E);
        const int blocks_g = (N_NODES * 64 + 255) / 256;
        k_gather<<<blocks_g, 256, 0, stream>>>(start, esrc, s_l, s_r, zbf, out);
    } else {
        k1_z_scores<<<blocks_k1, 256, 0, stream>>>(h, fc_w, attn_w, zbf, s_l, s_r,
                                                   nullptr, denom, out, 1);
        const long long tot = (long long)E * 8;
        const int blocks_k3 = (int)((tot + 255) / 256);
        k3_edges<<<blocks_k3, 256, 0, stream>>>(src, dst, s_l, s_r, zbf, denom, out, E);
        const int blocks_k4 = (N_NODES * OUT_DIM + 255) / 256;
        k4_finalize<<<blocks_k4, 256, 0, stream>>>(denom, out);
    }
}